// Round 10
// baseline (23326.309 us; speedup 1.0000x reference)
//
#include <hip/hip_runtime.h>
#include <math.h>

typedef __attribute__((ext_vector_type(8))) short short8v;
typedef __attribute__((ext_vector_type(4))) float float4v;

#if defined(__has_builtin)
#if __has_builtin(__builtin_amdgcn_global_load_lds)
#define USE_GLL 1
#endif
#endif
#ifndef USE_GLL
#define USE_GLL 0
#endif

__device__ __forceinline__ float gelu_f(float v) {
    return 0.5f * v * (1.0f + erff(v * 0.70710678118654752440f));
}

__device__ __forceinline__ unsigned short bf16r(float f) {
    unsigned u = __float_as_uint(f);
    u += 0x7FFFu + ((u >> 16) & 1u);
    return (unsigned short)(u >> 16);
}

__device__ __forceinline__ float bf2f(unsigned short s) {
    return __uint_as_float(((unsigned)s) << 16);
}

// ---------------------------------------------------------------------------
__global__ void dump_k(float* __restrict__ out, int n, float val) {
    int t = blockIdx.x * 256 + threadIdx.x;
    if (t < n) out[t] = val;
}

// ---------------------------------------------------------------------------
// Batched transpose-convert: in[R][Cc] f32 -> out[Cc][R] bf16; grid.z = layers.
// ---------------------------------------------------------------------------
__global__ void tc_k(const float* __restrict__ in0, unsigned short* __restrict__ out0,
                     int R, int Cc, long long ils, long long ols) {
    __shared__ float tile[32][33];
    int l = blockIdx.z;
    const float* in = in0 + (size_t)l * ils;
    unsigned short* out = out0 + (size_t)l * ols;
    int t = threadIdx.x;
    int tx = t & 31, ty = t >> 5;
    int r0 = blockIdx.x * 32, c0 = blockIdx.y * 32;
#pragma unroll
    for (int i = 0; i < 4; ++i) {
        int r = r0 + ty + i * 8, c = c0 + tx;
        tile[ty + i * 8][tx] = (r < R && c < Cc) ? in[(size_t)r * Cc + c] : 0.f;
    }
    __syncthreads();
#pragma unroll
    for (int i = 0; i < 4; ++i) {
        int c = c0 + ty + i * 8, r = r0 + tx;
        if (c < Cc && r < R) out[(size_t)c * R + r] = bf16r(tile[tx][ty + i * 8]);
    }
}

// ---------------------------------------------------------------------------
// Batched fproj fold (see round 7). grid ((2E+63)/64, 1, layers), block 256.
// ---------------------------------------------------------------------------
__global__ void fold_k(const float* __restrict__ Wq0, const float* __restrict__ Wk0,
                       const float* __restrict__ fp0, unsigned short* __restrict__ Wt0,
                       int E, int HD, int mode) {
    extern __shared__ float fpS[];
    int l = blockIdx.z;
    long long EE = (long long)E * E;
    const float* fp = fp0 + (size_t)l * HD * HD;
    unsigned short* Wt = Wt0 + (size_t)l * 3 * EE;
    int t = threadIdx.x;
    int n0 = blockIdx.x * 64;
    int n = n0 + (t & 63);
    int cg = t >> 6;

    int i0 = 0;
    if (mode == 0) {
        for (int idx = t; idx < HD * HD; idx += 256) fpS[idx] = fp[idx];
    } else if (mode == 1) {
        int base = (n0 < E) ? n0 : n0 - E;
        i0 = base % HD;
        for (int idx = t; idx < HD * 64; idx += 256)
            fpS[idx] = fp[(size_t)(idx >> 6) * HD + i0 + (idx & 63)];
    }
    __syncthreads();
    if (n >= 2 * E) return;
    int s = (n >= E) ? 1 : 0;
    int idd = n - s * E;
    int h = idd / HD, i = idd % HD;
    const float* W = (s ? Wk0 : Wq0) + (size_t)l * EE;
    for (int c = cg; c < E; c += 4) {
        const float* Wr = W + (size_t)c * E + h * HD;
        float acc = 0.f;
        if (mode == 0) {
            for (int d = 0; d < HD; ++d) acc += Wr[d] * fpS[d * HD + i];
        } else if (mode == 1) {
            for (int d = 0; d < HD; ++d) acc += Wr[d] * fpS[d * 64 + (i - i0)];
        } else {
            for (int d = 0; d < HD; ++d) acc += Wr[d] * fp[(size_t)d * HD + i];
        }
        Wt[(size_t)n * E + c] = bf16r(acc);
    }
}

// ---------------------------------------------------------------------------
// Batched bias fold
// ---------------------------------------------------------------------------
__global__ void biasfold_k(const float* __restrict__ bq0, const float* __restrict__ bk0,
                           const float* __restrict__ bv0, const float* __restrict__ fp0,
                           float* __restrict__ bqkv0, int E, int HD) {
    int l = blockIdx.z;
    const float* bq = bq0 + (size_t)l * E;
    const float* bk = bk0 + (size_t)l * E;
    const float* bv = bv0 + (size_t)l * E;
    const float* fp = fp0 + (size_t)l * HD * HD;
    float* bqkv = bqkv0 + (size_t)l * 3 * E;
    int c = blockIdx.x * 256 + threadIdx.x;
    if (c >= 3 * E) return;
    if (c < 2 * E) {
        int mat = c / E, cc = c % E, h = cc / HD, j = cc % HD;
        const float* bb = mat ? bk : bq;
        float s = 0.f;
        for (int d = 0; d < HD; ++d) s += bb[h * HD + d] * fp[(size_t)d * HD + j];
        bqkv[c] = s;
    } else {
        bqkv[c] = bv[c - 2 * E];
    }
}

// ---------------------------------------------------------------------------
// gemm2_k: 128x128x64 fallback GEMM (proven; see round 8). op: 0 f32 store,
// 1 gelu->bf16, 2 f32 +=, 3 bf16 store.
// ---------------------------------------------------------------------------
__global__ __launch_bounds__(512) void gemm2_k(
        const unsigned short* __restrict__ A, int lda,
        const unsigned short* __restrict__ Bt, int ldbt,
        void* __restrict__ Cv, int ldc,
        const float* __restrict__ bias,
        int M, int Nn, int K, int op, int al, int nNt) {
    __shared__ unsigned short Ab[128 * 64];
    __shared__ unsigned short Bb[128 * 64];
    int t = threadIdx.x;
    int nwg = gridDim.x;
    int orig = blockIdx.x;
    int xcd = orig & 7, pos = orig >> 3;
    int q = nwg >> 3, r = nwg & 7;
    int wgid = (xcd < r ? xcd * (q + 1) : r * (q + 1) + (xcd - r) * q) + pos;
    int m0 = (wgid / nNt) * 128, n0 = (wgid % nNt) * 128;
    int w = t >> 6, lane = t & 63;
    int wm = w >> 2, wn = w & 3;
    int lrow = lane & 15, lk = lane >> 4;

    float4v acc[4][2];
#pragma unroll
    for (int fa = 0; fa < 4; ++fa)
#pragma unroll
        for (int fb = 0; fb < 2; ++fb) acc[fa][fb] = (float4v){0.f, 0.f, 0.f, 0.f};

    int srow8 = lane >> 3;
    int sch = lane & 7;
    bool fastA = al && (m0 + 128 <= M);
    bool fastB = al && (n0 + 128 <= Nn);

    for (int k0 = 0; k0 < K; k0 += 64) {
        bool fullK = (k0 + 64 <= K);
        __syncthreads();
#if USE_GLL
        if (fastA && fullK) {
#pragma unroll
            for (int it = 0; it < 2; ++it) {
                int rr = w * 16 + it * 8 + srow8;
                const unsigned short* g = A + (size_t)(m0 + rr) * lda + k0 + ((sch ^ (rr & 7)) << 3);
                __builtin_amdgcn_global_load_lds((const void*)g, (void*)&Ab[(w * 16 + it * 8) * 64], 16, 0, 0);
            }
        } else
#endif
        {
#pragma unroll
            for (int cc = 0; cc < 2; ++cc) {
                int c = t + cc * 512;
                int row = c >> 3, ch = c & 7;
                int gm = m0 + row, gk = k0 + ch * 8;
                short8v v = {0, 0, 0, 0, 0, 0, 0, 0};
                if (gm < M) {
                    if (al && gk + 8 <= K) {
                        v = *(const short8v*)(A + (size_t)gm * lda + gk);
                    } else {
                        const unsigned short* p = A + (size_t)gm * lda;
#pragma unroll
                        for (int j = 0; j < 8; ++j)
                            if (gk + j < K) v[j] = (short)p[gk + j];
                    }
                }
                *(short8v*)&Ab[row * 64 + ((ch ^ (row & 7)) << 3)] = v;
            }
        }
#if USE_GLL
        if (fastB && fullK) {
#pragma unroll
            for (int it = 0; it < 2; ++it) {
                int rr = w * 16 + it * 8 + srow8;
                const unsigned short* g = Bt + (size_t)(n0 + rr) * ldbt + k0 + ((sch ^ (rr & 7)) << 3);
                __builtin_amdgcn_global_load_lds((const void*)g, (void*)&Bb[(w * 16 + it * 8) * 64], 16, 0, 0);
            }
        } else
#endif
        {
#pragma unroll
            for (int cc = 0; cc < 2; ++cc) {
                int c = t + cc * 512;
                int row = c >> 3, ch = c & 7;
                int gn = n0 + row, gk = k0 + ch * 8;
                short8v v = {0, 0, 0, 0, 0, 0, 0, 0};
                if (gn < Nn) {
                    if (al && gk + 8 <= K) {
                        v = *(const short8v*)(Bt + (size_t)gn * ldbt + gk);
                    } else {
                        const unsigned short* p = Bt + (size_t)gn * ldbt;
#pragma unroll
                        for (int j = 0; j < 8; ++j)
                            if (gk + j < K) v[j] = (short)p[gk + j];
                    }
                }
                *(short8v*)&Bb[row * 64 + ((ch ^ (row & 7)) << 3)] = v;
            }
        }
        __syncthreads();
#pragma unroll
        for (int ks = 0; ks < 2; ++ks) {
            short8v af[4], bf[2];
#pragma unroll
            for (int fa = 0; fa < 4; ++fa) {
                int row = wm * 64 + fa * 16 + lrow;
                af[fa] = *(const short8v*)&Ab[row * 64 + (((ks * 4 + lk) ^ (row & 7)) << 3)];
            }
#pragma unroll
            for (int fb = 0; fb < 2; ++fb) {
                int row = wn * 32 + fb * 16 + lrow;
                bf[fb] = *(const short8v*)&Bb[row * 64 + (((ks * 4 + lk) ^ (row & 7)) << 3)];
            }
#pragma unroll
            for (int fa = 0; fa < 4; ++fa)
#pragma unroll
                for (int fb = 0; fb < 2; ++fb)
                    acc[fa][fb] = __builtin_amdgcn_mfma_f32_16x16x32_bf16(
                        af[fa], bf[fb], acc[fa][fb], 0, 0, 0);
        }
    }
    float* Cf = (float*)Cv;
    unsigned short* Cu = (unsigned short*)Cv;
#pragma unroll
    for (int fb = 0; fb < 2; ++fb) {
        int col = n0 + wn * 32 + fb * 16 + lrow;
        if (col >= Nn) continue;
        float bb = bias ? bias[col] : 0.f;
#pragma unroll
        for (int fa = 0; fa < 4; ++fa) {
#pragma unroll
            for (int q2 = 0; q2 < 4; ++q2) {
                int row = m0 + wm * 64 + fa * 16 + lk * 4 + q2;
                if (row >= M) continue;
                float v = acc[fa][fb][q2] + bb;
                size_t idx = (size_t)row * ldc + col;
                if (op == 0) Cf[idx] = v;
                else if (op == 1) Cu[idx] = bf16r(gelu_f(v));
                else if (op == 2) Cf[idx] += v;
                else Cu[idx] = bf16r(v);
            }
        }
    }
}

// ---------------------------------------------------------------------------
// gemm256_k: 256x256x64 8-phase GEMM (T2+T3+T4+T5). Requires M%256==0,
// Nn%256==0, K%128==0, aligned. 512 thr, 8 waves (2Mx4N), per-wave out 128x64.
// LDS 128 KiB: A slots [0,16384),[16384,32768); B slots +32768 (shorts).
// Per K-tile t (slot t&1), 4 phases: phase p ds_reads A fa{2p,2p+1} (+all B at
// p=0, held in regs), stages one half-tile (A halves of t+1 -> other slot at
// p=0,1; B halves of t+2 -> current slot at p=2,3 — safe: B consumed at p=0),
// 16 MFMA between raw barriers with setprio; counted vmcnt(4) at p=3 only.
// ---------------------------------------------------------------------------
__global__ __launch_bounds__(512, 2) void gemm256_k(
        const unsigned short* __restrict__ A, int lda,
        const unsigned short* __restrict__ Bt, int ldbt,
        void* __restrict__ Cv, int ldc,
        const float* __restrict__ bias,
        int M, int Nn, int K, int op, int nNt) {
    extern __shared__ unsigned short lds[];
    const int t = threadIdx.x;
    const int w = t >> 6, lane = t & 63;
    const int wm = w >> 2, wn = w & 3;
    const int lrow = lane & 15, lk = lane >> 4;
    int nwg = gridDim.x, orig = blockIdx.x;
    int xcd = orig & 7, pos = orig >> 3;
    int q = nwg >> 3, r = nwg & 7;
    int wgid = (xcd < r ? xcd * (q + 1) : r * (q + 1) + (xcd - r) * q) + pos;
    const int m0 = (wgid / nNt) * 256, n0 = (wgid % nNt) * 256;

    const int sg_row = lane >> 3;                 // 0..7
    const int sg_ch = (lane & 7) ^ sg_row;        // pre-swizzled global chunk

    float4v acc[8][4];
#pragma unroll
    for (int fa = 0; fa < 8; ++fa)
#pragma unroll
        for (int fb = 0; fb < 4; ++fb) acc[fa][fb] = (float4v){0.f, 0.f, 0.f, 0.f};

    const int nk = K >> 6;

#if USE_GLL
#define STAGE_A(KT, HALF, SLOT)                                                          \
    {                                                                                    \
        _Pragma("unroll")                                                                \
        for (int it = 0; it < 2; ++it) {                                                 \
            int rl = (HALF) * 128 + w * 16 + it * 8;                                     \
            const unsigned short* g = A + (size_t)(m0 + rl + sg_row) * lda +             \
                                      (KT) * 64 + (sg_ch << 3);                          \
            __builtin_amdgcn_global_load_lds((const void*)g,                             \
                (void*)&lds[(size_t)(SLOT) * 16384 + (size_t)rl * 64], 16, 0, 0);        \
        }                                                                                \
    }
#define STAGE_B(KT, HALF, SLOT)                                                          \
    {                                                                                    \
        _Pragma("unroll")                                                                \
        for (int it = 0; it < 2; ++it) {                                                 \
            int rl = (HALF) * 128 + w * 16 + it * 8;                                     \
            const unsigned short* g = Bt + (size_t)(n0 + rl + sg_row) * ldbt +           \
                                      (KT) * 64 + (sg_ch << 3);                          \
            __builtin_amdgcn_global_load_lds((const void*)g,                             \
                (void*)&lds[32768 + (size_t)(SLOT) * 16384 + (size_t)rl * 64], 16, 0, 0);\
        }                                                                                \
    }
#else
    // register-staging fallback (same layout)
#define STAGE_A(KT, HALF, SLOT)                                                          \
    {                                                                                    \
        _Pragma("unroll")                                                                \
        for (int it = 0; it < 2; ++it) {                                                 \
            int rl = (HALF) * 128 + w * 16 + it * 8;                                     \
            const unsigned short* g = A + (size_t)(m0 + rl + sg_row) * lda +             \
                                      (KT) * 64 + (sg_ch << 3);                          \
            *(short8v*)&lds[(size_t)(SLOT) * 16384 + (size_t)(rl + sg_row) * 64 +        \
                            ((size_t)((lane & 7)) << 3)] = *(const short8v*)g;           \
        }                                                                                \
    }
#define STAGE_B(KT, HALF, SLOT)                                                          \
    {                                                                                    \
        _Pragma("unroll")                                                                \
        for (int it = 0; it < 2; ++it) {                                                 \
            int rl = (HALF) * 128 + w * 16 + it * 8;                                     \
            const unsigned short* g = Bt + (size_t)(n0 + rl + sg_row) * ldbt +           \
                                      (KT) * 64 + (sg_ch << 3);                          \
            *(short8v*)&lds[32768 + (size_t)(SLOT) * 16384 + (size_t)(rl + sg_row) * 64 +\
                            ((size_t)((lane & 7)) << 3)] = *(const short8v*)g;           \
        }                                                                                \
    }
#endif

    // ---- prologue: tile 0 (A0,A1,B0,B1) -> slot 0; tile 1 B halves -> slot 1
    STAGE_A(0, 0, 0); STAGE_A(0, 1, 0); STAGE_B(0, 0, 0); STAGE_B(0, 1, 0);
    if (nk > 1) { STAGE_B(1, 0, 1); STAGE_B(1, 1, 1); }
    __builtin_amdgcn_sched_barrier(0);
#if USE_GLL
    if (nk > 1) asm volatile("s_waitcnt vmcnt(4)" ::: "memory");
    else        asm volatile("s_waitcnt vmcnt(0)" ::: "memory");
#else
    asm volatile("s_waitcnt vmcnt(0)" ::: "memory");
#endif
    __builtin_amdgcn_sched_barrier(0);
    __builtin_amdgcn_s_barrier();
    __builtin_amdgcn_sched_barrier(0);

    short8v breg[4][2];
    for (int tt = 0; tt < nk; ++tt) {
        const int s = tt & 1, sn = s ^ 1;
        const bool doA = (tt + 1) < nk;
        const bool doB = (tt + 2) < nk;
        const size_t aBase = (size_t)s * 16384;
        const size_t bBase = 32768 + (size_t)s * 16384;
#pragma unroll
        for (int p = 0; p < 4; ++p) {
            short8v areg[2][2];
            if (p == 0) {
#pragma unroll
                for (int fb = 0; fb < 4; ++fb) {
                    int row = wn * 64 + fb * 16 + lrow;
#pragma unroll
                    for (int ks = 0; ks < 2; ++ks)
                        breg[fb][ks] = *(const short8v*)&lds[bBase + (size_t)row * 64 +
                            ((((ks << 2) + lk) ^ (row & 7)) << 3)];
                }
            }
#pragma unroll
            for (int i = 0; i < 2; ++i) {
                int row = wm * 128 + (2 * p + i) * 16 + lrow;
#pragma unroll
                for (int ks = 0; ks < 2; ++ks)
                    areg[i][ks] = *(const short8v*)&lds[aBase + (size_t)row * 64 +
                        ((((ks << 2) + lk) ^ (row & 7)) << 3)];
            }
            if (p == 0 && doA) STAGE_A(tt + 1, 0, sn);
            if (p == 1 && doA) STAGE_A(tt + 1, 1, sn);
            if (p == 2 && doB) STAGE_B(tt + 2, 0, s);
            if (p == 3 && doB) STAGE_B(tt + 2, 1, s);
            __builtin_amdgcn_sched_barrier(0);
            __builtin_amdgcn_s_barrier();
            __builtin_amdgcn_sched_barrier(0);
            __builtin_amdgcn_s_setprio(1);
#pragma unroll
            for (int i = 0; i < 2; ++i)
#pragma unroll
                for (int fb = 0; fb < 4; ++fb)
#pragma unroll
                    for (int ks = 0; ks < 2; ++ks)
                        acc[2 * p + i][fb] = __builtin_amdgcn_mfma_f32_16x16x32_bf16(
                            areg[i][ks], breg[fb][ks], acc[2 * p + i][fb], 0, 0, 0);
            __builtin_amdgcn_s_setprio(0);
            __builtin_amdgcn_sched_barrier(0);
            if (p == 3) {
#if USE_GLL
                if (doB)      asm volatile("s_waitcnt vmcnt(4)" ::: "memory");
                else if (doA) asm volatile("s_waitcnt vmcnt(0)" ::: "memory");
#else
                asm volatile("s_waitcnt vmcnt(0)" ::: "memory");
#endif
                __builtin_amdgcn_sched_barrier(0);
            }
            __builtin_amdgcn_s_barrier();
            __builtin_amdgcn_sched_barrier(0);
        }
    }
#undef STAGE_A
#undef STAGE_B

    float* Cf = (float*)Cv;
    unsigned short* Cu = (unsigned short*)Cv;
#pragma unroll
    for (int fb = 0; fb < 4; ++fb) {
        int col = n0 + wn * 64 + fb * 16 + lrow;
        float bb = bias ? bias[col] : 0.f;
#pragma unroll
        for (int fa = 0; fa < 8; ++fa) {
#pragma unroll
            for (int q2 = 0; q2 < 4; ++q2) {
                int row = m0 + wm * 128 + fa * 16 + lk * 4 + q2;
                float v = acc[fa][fb][q2] + bb;
                size_t idx = (size_t)row * ldc + col;
                if (op == 0) Cf[idx] = v;
                else if (op == 1) Cu[idx] = bf16r(gelu_f(v));
                else if (op == 2) Cf[idx] += v;
                else Cu[idx] = bf16r(v);
            }
        }
    }
}

// ---------------------------------------------------------------------------
// Host-side GEMM dispatch: gemm256 fast path for full 256-row stripes,
// gemm2 for the remainder / incompatible shapes.
// ---------------------------------------------------------------------------
static inline void launch_gemm(const unsigned short* A, int lda,
                               const unsigned short* Bt, int ldbt,
                               void* Cv, int ldc, const float* bias,
                               int M, int Nn, int K, int op, int al,
                               hipStream_t stream) {
    int M256 = 0;
    if (al && Nn % 256 == 0 && K % 128 == 0 && K >= 128) M256 = (M / 256) * 256;
    if (M256 > 0) {
        int nNt = Nn / 256;
        int grid = (M256 / 256) * nNt;
        gemm256_k<<<grid, 512, 131072, stream>>>(A, lda, Bt, ldbt, Cv, ldc, bias,
                                                 M256, Nn, K, op, nNt);
    }
    int Mr = M - M256;
    if (Mr > 0) {
        int esz = (op == 0 || op == 2) ? 4 : 2;
        int nNt = (Nn + 127) / 128;
        int grid = ((Mr + 127) / 128) * nNt;
        gemm2_k<<<grid, 512, 0, stream>>>(A + (size_t)M256 * lda, lda, Bt, ldbt,
                                          (void*)((char*)Cv + (size_t)M256 * ldc * esz),
                                          ldc, bias, Mr, Nn, K, op, al, nNt);
    }
}

// ---------------------------------------------------------------------------
// Patch embed + cls + pos -> x f32. grid (N, B), block 256.
// ---------------------------------------------------------------------------
__global__ void embed_lds_k(const float* __restrict__ src, const float* __restrict__ cw,
                            const float* __restrict__ cb, const float* __restrict__ pos,
                            const float* __restrict__ cls, float* __restrict__ x,
                            int C, int IMG, int P, int m, int E, int N, int K) {
    extern __shared__ float patch[];
    int n = blockIdx.x, b = blockIdx.y, t = threadIdx.x;
    if (n == 0) {
        for (int e = t; e < E; e += 256)
            x[((size_t)b * N) * E + e] = cls[e] + pos[e];
        return;
    }
    int p = n - 1, ph = p / m, pw = p % m;
    int P2 = P * P;
    for (int mm = t; mm < K; mm += 256) {
        int c = mm / P2, rem = mm % P2, i = rem / P, j = rem % P;
        patch[mm] = src[(((size_t)b * C + c) * IMG + ph * P + i) * IMG + pw * P + j];
    }
    __syncthreads();
    for (int e = t; e < E; e += 256) {
        float acc = cb[e];
        const float* wr = cw + (size_t)e * K;
        for (int mm = 0; mm < K; ++mm) acc += patch[mm] * wr[mm];
        x[((size_t)b * N + n) * E + e] = acc + pos[(size_t)n * E + e];
    }
}

__global__ void embed_dir_k(const float* __restrict__ src, const float* __restrict__ cw,
                            const float* __restrict__ cb, const float* __restrict__ pos,
                            const float* __restrict__ cls, float* __restrict__ x,
                            int C, int IMG, int P, int m, int E, int N, int K) {
    int n = blockIdx.x, b = blockIdx.y, t = threadIdx.x;
    if (n == 0) {
        for (int e = t; e < E; e += 256)
            x[((size_t)b * N) * E + e] = cls[e] + pos[e];
        return;
    }
    int p = n - 1, ph = p / m, pw = p % m;
    int P2 = P * P;
    for (int e = t; e < E; e += 256) {
        float acc = cb[e];
        const float* wr = cw + (size_t)e * K;
        for (int mm = 0; mm < K; ++mm) {
            int c = mm / P2, rem = mm % P2, i = rem / P, j = rem % P;
            acc += src[(((size_t)b * C + c) * IMG + ph * P + i) * IMG + pw * P + j] * wr[mm];
        }
        x[((size_t)b * N + n) * E + e] = acc + pos[(size_t)n * E + e];
    }
}

// ---------------------------------------------------------------------------
// LayerNorm rows of x f32 -> xg bf16. grid ceil(TOK/4), block 256.
// ---------------------------------------------------------------------------
__global__ void ln_k(const float* __restrict__ x, const float* __restrict__ g,
                     const float* __restrict__ b, unsigned short* __restrict__ xg,
                     int TOK, int E, float invE) {
    int row = blockIdx.x * 4 + (threadIdx.x >> 6);
    int lane = threadIdx.x & 63;
    if (row >= TOK) return;
    const float* xr = x + (size_t)row * E;
    float s = 0.f;
    for (int e = lane; e < E; e += 64) s += xr[e];
#pragma unroll
    for (int mm = 32; mm >= 1; mm >>= 1) s += __shfl_xor(s, mm, 64);
    float mean = s * invE;
    float v = 0.f;
    for (int e = lane; e < E; e += 64) { float d = xr[e] - mean; v += d * d; }
#pragma unroll
    for (int mm = 32; mm >= 1; mm >>= 1) v += __shfl_xor(v, mm, 64);
    float inv = rsqrtf(v * invE + 1e-5f);
    unsigned short* orow = xg + (size_t)row * E;
    for (int e = lane; e < E; e += 64)
        orow[e] = bf16r((xr[e] - mean) * inv * g[e] + b[e]);
}

// ---------------------------------------------------------------------------
// Attention core on bf16 qkv + fused LN2 (see round 9). grid (Gg, nimg).
// ---------------------------------------------------------------------------
__global__ void attn_sm_k(const unsigned short* __restrict__ qkv, float* __restrict__ x,
                          unsigned short* __restrict__ xg,
                          const float* __restrict__ g2, const float* __restrict__ b2,
                          int img0, int N, int E, int H, int HD, float rscale,
                          float invE, int vec) {
    extern __shared__ float sc[];
    int g = blockIdx.x, im = blockIdx.y, t = threadIdx.x;
    int t0 = g * 8, nv = min(8, N - t0);
    int E3 = 3 * E;
    const unsigned short* qb = qkv + ((size_t)im * N + t0) * E3;
    size_t rowbase = ((size_t)(img0 + im)) * N + t0;
    float* xb = x + rowbase * E;
    for (int idx = t; idx < H * 64; idx += 256) {
        int h = idx >> 6, qr = (idx >> 3) & 7, kr = idx & 7;
        float s = 0.f;
        if (qr < nv && kr < nv) {
            const unsigned short* qp = qb + (size_t)qr * E3 + h * HD;
            const unsigned short* kp = qb + (size_t)kr * E3 + E + h * HD;
            if (vec) {
                for (int d = 0; d < HD; d += 8) {
                    short8v qv = *(const short8v*)(qp + d);
                    short8v kv = *(const short8v*)(kp + d);
#pragma unroll
                    for (int j = 0; j < 8; ++j)
                        s += bf2f((unsigned short)qv[j]) * bf2f((unsigned short)kv[j]);
                }
            } else {
                for (int d = 0; d < HD; ++d)
                    s += bf2f(qp[d]) * bf2f(kp[d]);
            }
        }
        sc[idx] = s * rscale;
    }
    __syncthreads();
    for (int idx = t; idx < H * 8; idx += 256) {
        int h = idx >> 3, qr = idx & 7;
        if (qr < nv) {
            float* row = sc + h * 64 + qr * 8;
            float mx = -1e30f;
            for (int k = 0; k < nv; ++k) mx = fmaxf(mx, row[k]);
            float sum = 0.f;
            for (int k = 0; k < nv; ++k) { float e = expf(row[k] - mx); row[k] = e; sum += e; }
            float inv = 1.f / sum;
            for (int k = 0; k < nv; ++k) row[k] *= inv;
        }
    }
    __syncthreads();
    for (int c = t; c < E; c += 256) {
        int h = c / HD;
        const float* srow = sc + h * 64;
        float vcol[8];
#pragma unroll
        for (int k = 0; k < 8; ++k)
            vcol[k] = (k < nv) ? bf2f(qb[(size_t)k * E3 + 2 * E + c]) : 0.f;
        for (int r = 0; r < nv; ++r) {
            float o = 0.f;
#pragma unroll
            for (int k = 0; k < 8; ++k) o += srow[r * 8 + k] * vcol[k];
            xb[(size_t)r * E + c] += o;
        }
    }
    __syncthreads();
    int w = t >> 6, lane = t & 63;
#pragma unroll
    for (int rr = 0; rr < 2; ++rr) {
        int r = w + rr * 4;
        if (r >= nv) continue;
        const float* xr = xb + (size_t)r * E;
        float s = 0.f;
        for (int e = lane; e < E; e += 64) s += xr[e];
#pragma unroll
        for (int mm = 32; mm >= 1; mm >>= 1) s += __shfl_xor(s, mm, 64);
        float mean = s * invE;
        float v = 0.f;
        for (int e = lane; e < E; e += 64) { float d = xr[e] - mean; v += d * d; }
#pragma unroll
        for (int mm = 32; mm >= 1; mm >>= 1) v += __shfl_xor(v, mm, 64);
        float inv = rsqrtf(v * invE + 1e-5f);
        unsigned short* orow = xg + (rowbase + r) * E;
        for (int e = lane; e < E; e += 64)
            orow[e] = bf16r((xr[e] - mean) * inv * g2[e] + b2[e]);
    }
}

// ---------------------------------------------------------------------------
__global__ void head_k(const float* __restrict__ fw, const float* __restrict__ fb,
                       const float* __restrict__ x, float* __restrict__ out,
                       int Bc, int N, int E, int NC) {
    int idx = blockIdx.x * 256 + threadIdx.x;
    if (idx < Bc * NC) {
        int b = idx / NC, nc = idx % NC;
        float acc = fb[nc];
        const float* xr = x + (size_t)b * N * E;
        for (int e = 0; e < E; ++e) acc += xr[e] * fw[(size_t)e * NC + nc];
        out[idx] = acc;
    }
}

// ---------------------------------------------------------------------------
static int isqrt_i(long long v) {
    if (v < 0) return -1;
    long long r = (long long)(sqrt((double)v) + 0.5);
    while (r * r > v) --r;
    while ((r + 1) * (r + 1) <= v) ++r;
    return (int)r;
}

extern "C" void kernel_launch(void* const* d_in, const int* in_sizes, int n_in,
                              void* d_out, int out_size, void* d_ws, size_t ws_size,
                              hipStream_t stream) {
    float* out = (float*)d_out;
    int nblk_out = (out_size + 255) / 256;
#define DUMP(code, val) do { \
        dump_k<<<nblk_out, 256, 0, stream>>>(out, out_size, (float)((code) * 1000000.0 + (double)(val))); \
        return; } while (0)

    if (n_in != 22) DUMP(1, n_in < 999999 ? n_in : 999999);
    const int* S = in_sizes;

    int E = S[2];
    if (E <= 0 || S[4] != E) DUMP(2, 4);
    if (S[6] % E) DUMP(2, 6);
    int L = S[6] / E;
    if (L <= 0) DUMP(2, 6);
    long long EE = (long long)E * E;
    if (S[5] != L * EE || S[7] != L * EE || S[9] != L * EE) DUMP(2, 5);
    if (S[8] != L * E || S[10] != L * E) DUMP(2, 8);
    if (S[12] != L * E || S[13] != L * E || S[14] != L * E || S[15] != L * E) DUMP(2, 12);
    if (S[19] != L * E) DUMP(2, 19);
    if (S[11] % L) DUMP(2, 11);
    int HD = isqrt_i(S[11] / L);
    if ((long long)HD * HD * L != S[11] || HD <= 0 || E % HD) DUMP(3, HD > 0 ? HD : 0);
    int H = E / HD;
    if (S[17] % L) DUMP(2, 17);
    int FF = S[17] / L;
    if (S[16] != (long long)L * E * FF) DUMP(2, 16);
    if (S[18] != (long long)L * FF * E) DUMP(2, 18);
    if (S[3] % E) DUMP(2, 3);
    int N = S[3] / E;
    int m = isqrt_i(N - 1);
    if (m <= 0 || m * m != N - 1) DUMP(4, N < 999999 ? N : 999999);
    int NC = S[21];
    if (NC <= 0 || S[20] != (long long)E * NC) DUMP(2, 20);
    if (out_size % NC) DUMP(8, out_size < 999999 ? out_size : 999999);
    int Bc = out_size / NC;
    if (S[1] % E) DUMP(2, 1);
    int K = S[1] / E;
    static const int corder[12] = {3, 4, 1, 2, 8, 16, 6, 12, 32, 64, 24, 48};
    int C = -1, P = -1;
    for (int ci = 0; ci < 12; ++ci) {
        int c = corder[ci];
        if (K % c) continue;
        int p = isqrt_i(K / c);
        if (p > 0 && p * p * c == K) {
            long long img = (long long)p * m;
            if ((long long)Bc * c * img * img == S[0]) { C = c; P = p; break; }
        }
    }
    if (C < 0) DUMP(5, K < 999999 ? K : 999999);
    int IMG = P * m;
    int TOK = Bc * N;
    int Gg = (N + 7) / 8;
    int E3 = 3 * E;
    int al = ((E % 8) == 0 && (FF % 8) == 0) ? 1 : 0;
    int vecA = (al && (HD % 8) == 0) ? 1 : 0;

    // allow 128 KiB dynamic LDS for gemm256 (idempotent, capture-safe)
    (void)hipFuncSetAttribute((const void*)gemm256_k,
                              hipFuncAttributeMaxDynamicSharedMemorySize, 131072);

    int fmode;
    if (HD <= 64) fmode = 0;
    else if ((E % 64) == 0 && HD <= 256) fmode = 1;
    else fmode = 2;
    size_t fold_sh = (fmode == 0) ? (size_t)HD * HD * 4
                   : (fmode == 1) ? (size_t)HD * 64 * 4 : 16;

    size_t b_x  = ((size_t)TOK * E * 4 + 255) & ~(size_t)255;
    size_t b_xg = ((size_t)TOK * E * 2 + 255) & ~(size_t)255;
    size_t s_wt  = ((size_t)E3 * E * 2 + 255) & ~(size_t)255;
    size_t s_wff = ((size_t)E * FF * 2 + 255) & ~(size_t)255;
    size_t s_bq  = ((size_t)E3 * 4 + 255) & ~(size_t)255;
    size_t perL = s_wt + 2 * s_wff + s_bq;
    size_t minbuf = (size_t)N * E3 * 2;
    size_t fb2 = (size_t)128 * FF * 2;
    if (fb2 > minbuf) minbuf = fb2;

    int LW;
    if (b_x + b_xg + perL * L + minbuf <= ws_size) LW = L;
    else if (b_x + b_xg + perL + minbuf <= ws_size) LW = 1;
    else { DUMP(6, (double)(ws_size >> 20)); }

    char* wsb = (char*)d_ws;
    size_t off = 0;
    float* x = (float*)(wsb + off); off += b_x;
    unsigned short* xg = (unsigned short*)(wsb + off); off += b_xg;
    unsigned short* Wt_base = (unsigned short*)(wsb + off); off += s_wt * LW;
    unsigned short* w1t_base = (unsigned short*)(wsb + off); off += s_wff * LW;
    unsigned short* w2t_base = (unsigned short*)(wsb + off); off += s_wff * LW;
    float* bq_base = (float*)(wsb + off); off += s_bq * LW;
    size_t buf_bytes = ws_size - off;
    unsigned short* bufu = (unsigned short*)(wsb + off);

    int CHI = (int)(buf_bytes / ((size_t)N * E3 * 2));
    if (CHI > Bc) CHI = Bc;
    long long chf_l = (long long)(buf_bytes / ((size_t)FF * 2));
    chf_l = (chf_l / 256) * 256;
    int CHF = chf_l > TOK ? TOK : (int)chf_l;
    if (CHI < 1 || CHF < 128) DUMP(6, (double)(ws_size >> 20));

    const float* src = (const float*)d_in[0];
    const float* cw  = (const float*)d_in[1];
    const float* cb  = (const float*)d_in[2];
    const float* pos = (const float*)d_in[3];
    const float* cls = (const float*)d_in[4];
    const float* Wq  = (const float*)d_in[5];
    const float* bq  = (const float*)d_in[6];
    const float* Wk  = (const float*)d_in[7];
    const float* bk  = (const float*)d_in[8];
    const float* Wv  = (const float*)d_in[9];
    const float* bv  = (const float*)d_in[10];
    const float* fp  = (const float*)d_in[11];
    const float* g1  = (const float*)d_in[12];
    const float* b1  = (const float*)d_in[13];
    const float* g2  = (const float*)d_in[14];
    const float* b2  = (const float*)d_in[15];
    const float* w1  = (const float*)d_in[16];
    const float* bb1 = (const float*)d_in[17];
    const float* w2  = (const float*)d_in[18];
    const float* bb2 = (const float*)d_in[19];
    const float* fcw = (const float*)d_in[20];
    const float* fcb = (const float*)d_in[21];

    float invE = 1.f / (float)E;
    float rscale = 1.f / sqrtf((float)HD);
    size_t wtL = (size_t)E3 * E;
    size_t wffL = (size_t)E * FF;

    size_t patch_sh = (size_t)K * sizeof(float);
    if (patch_sh <= 48000)
        embed_lds_k<<<dim3(N, Bc), 256, patch_sh, stream>>>(src, cw, cb, pos, cls, x,
                                                            C, IMG, P, m, E, N, K);
    else
        embed_dir_k<<<dim3(N, Bc), 256, 0, stream>>>(src, cw, cb, pos, cls, x,
                                                     C, IMG, P, m, E, N, K);

    int gx_fold = (2 * E + 63) / 64;
    if (LW == L) {
        fold_k<<<dim3(gx_fold, 1, L), 256, fold_sh, stream>>>(Wq, Wk, fp, Wt_base, E, HD, fmode);
        tc_k<<<dim3((E + 31) / 32, (E + 31) / 32, L), 256, 0, stream>>>(
            Wv, Wt_base + (size_t)2 * E * E, E, E, EE, wtL);
        tc_k<<<dim3((E + 31) / 32, (FF + 31) / 32, L), 256, 0, stream>>>(
            w1, w1t_base, E, FF, (long long)E * FF, wffL);
        tc_k<<<dim3((FF + 31) / 32, (E + 31) / 32, L), 256, 0, stream>>>(
            w2, w2t_base, FF, E, (long long)E * FF, wffL);
        biasfold_k<<<dim3((E3 + 255) / 256, 1, L), 256, 0, stream>>>(
            bq, bk, bv, fp, bq_base, E, HD);
    }

    int ln_grid = (TOK + 3) / 4;
    size_t attn_sh = (size_t)H * 64 * sizeof(float);

    for (int l = 0; l < L; ++l) {
        int lw = (LW == L) ? l : 0;
        unsigned short* Wt_l  = Wt_base + (size_t)lw * (s_wt / 2);
        unsigned short* w1t_l = w1t_base + (size_t)lw * (s_wff / 2);
        unsigned short* w2t_l = w2t_base + (size_t)lw * (s_wff / 2);
        float* bq_l = (float*)((char*)bq_base + (size_t)lw * s_bq);

        if (LW != L) {
            fold_k<<<dim3(gx_fold, 1, 1), 256, fold_sh, stream>>>(
                Wq + (size_t)l * EE, Wk + (size_t)l * EE, fp + (size_t)l * HD * HD,
                Wt_l, E, HD, fmode);
            tc_k<<<dim3((E + 31) / 32, (E + 31) / 32, 1), 256, 0, stream>>>(
                Wv + (size_t)l * EE, Wt_l + (size_t)2 * E * E, E, E, 0, 0);
            tc_k<<<dim3((E + 31) / 32, (FF + 31) / 32, 1), 256, 0, stream>>>(
                w1 + (size_t)l * E * FF, w1t_l, E, FF, 0, 0);
            tc_k<<<dim3((FF + 31) / 32, (E + 31) / 32, 1), 256, 0, stream>>>(
                w2 + (size_t)l * FF * E, w2t_l, FF, E, 0, 0);
            biasfold_k<<<dim3((E3 + 255) / 256, 1, 1), 256, 0, stream>>>(
                bq + (size_t)l * E, bk + (size_t)l * E, bv + (size_t)l * E,
                fp + (size_t)l * HD * HD, bq_l, E, HD);
        }

        // ---- LN1 -> xg bf16
        ln_k<<<ln_grid, 256, 0, stream>>>(x, g1 + (size_t)l * E, b1 + (size_t)l * E,
                                          xg, TOK, E, invE);
        // ---- QKV GEMM (bf16 out) + attention (+ fused LN2 -> xg)
        for (int img0 = 0; img0 < Bc; img0 += CHI) {
            int nimg = Bc - img0 < CHI ? Bc - img0 : CHI;
            int ntok = nimg * N;
            launch_gemm(xg + (size_t)img0 * N * E, E, Wt_l, E, bufu, E3, bq_l,
                        ntok, E3, E, 3, al, stream);
            attn_sm_k<<<dim3(Gg, nimg), 256, attn_sh, stream>>>(
                bufu, x, xg, g2 + (size_t)l * E, b2 + (size_t)l * E,
                img0, N, E, H, HD, rscale, invE, vecA);
        }
        // ---- FFN (xg already = LN2(x))
        for (int tok0 = 0; tok0 < TOK; tok0 += CHF) {
            int ntok = TOK - tok0 < CHF ? TOK - tok0 : CHF;
            launch_gemm(xg + (size_t)tok0 * E, E, w1t_l, E, bufu, FF,
                        bb1 + (size_t)l * FF, ntok, FF, E, 1, al, stream);
            launch_gemm(bufu, FF, w2t_l, FF, x + (size_t)tok0 * E, E,
                        bb2 + (size_t)l * E, ntok, E, FF, 2, al, stream);
        }
    }
    head_k<<<nblk_out, 256, 0, stream>>>(fcw, fcb, x, out, Bc, N, E, NC);
#undef DUMP
}

// Round 11
// 9997.883 us; speedup vs baseline: 2.3331x; 2.3331x over previous
//
#include <hip/hip_runtime.h>
#include <math.h>

typedef __attribute__((ext_vector_type(8))) short short8v;
typedef __attribute__((ext_vector_type(4))) short short4v;
typedef __attribute__((ext_vector_type(4))) float float4v;

#if defined(__has_builtin)
#if __has_builtin(__builtin_amdgcn_global_load_lds)
#define USE_GLL 1
#endif
#endif
#ifndef USE_GLL
#define USE_GLL 0
#endif

__device__ __forceinline__ float gelu_f(float v) {
    return 0.5f * v * (1.0f + erff(v * 0.70710678118654752440f));
}

__device__ __forceinline__ unsigned short bf16r(float f) {
    unsigned u = __float_as_uint(f);
    u += 0x7FFFu + ((u >> 16) & 1u);
    return (unsigned short)(u >> 16);
}

__device__ __forceinline__ float bf2f(unsigned short s) {
    return __uint_as_float(((unsigned)s) << 16);
}

// ---------------------------------------------------------------------------
__global__ void dump_k(float* __restrict__ out, int n, float val) {
    int t = blockIdx.x * 256 + threadIdx.x;
    if (t < n) out[t] = val;
}

// ---------------------------------------------------------------------------
// Batched transpose-convert: in[R][Cc] f32 -> out[Cc][R] bf16; grid.z = layers.
// ---------------------------------------------------------------------------
__global__ void tc_k(const float* __restrict__ in0, unsigned short* __restrict__ out0,
                     int R, int Cc, long long ils, long long ols) {
    __shared__ float tile[32][33];
    int l = blockIdx.z;
    const float* in = in0 + (size_t)l * ils;
    unsigned short* out = out0 + (size_t)l * ols;
    int t = threadIdx.x;
    int tx = t & 31, ty = t >> 5;
    int r0 = blockIdx.x * 32, c0 = blockIdx.y * 32;
#pragma unroll
    for (int i = 0; i < 4; ++i) {
        int r = r0 + ty + i * 8, c = c0 + tx;
        tile[ty + i * 8][tx] = (r < R && c < Cc) ? in[(size_t)r * Cc + c] : 0.f;
    }
    __syncthreads();
#pragma unroll
    for (int i = 0; i < 4; ++i) {
        int c = c0 + ty + i * 8, r = r0 + tx;
        if (c < Cc && r < R) out[(size_t)c * R + r] = bf16r(tile[tx][ty + i * 8]);
    }
}

// ---------------------------------------------------------------------------
// Batched fproj fold. grid ((2E+63)/64, 1, layers), block 256.
// ---------------------------------------------------------------------------
__global__ void fold_k(const float* __restrict__ Wq0, const float* __restrict__ Wk0,
                       const float* __restrict__ fp0, unsigned short* __restrict__ Wt0,
                       int E, int HD, int mode) {
    extern __shared__ float fpS[];
    int l = blockIdx.z;
    long long EE = (long long)E * E;
    const float* fp = fp0 + (size_t)l * HD * HD;
    unsigned short* Wt = Wt0 + (size_t)l * 3 * EE;
    int t = threadIdx.x;
    int n0 = blockIdx.x * 64;
    int n = n0 + (t & 63);
    int cg = t >> 6;

    int i0 = 0;
    if (mode == 0) {
        for (int idx = t; idx < HD * HD; idx += 256) fpS[idx] = fp[idx];
    } else if (mode == 1) {
        int base = (n0 < E) ? n0 : n0 - E;
        i0 = base % HD;
        for (int idx = t; idx < HD * 64; idx += 256)
            fpS[idx] = fp[(size_t)(idx >> 6) * HD + i0 + (idx & 63)];
    }
    __syncthreads();
    if (n >= 2 * E) return;
    int s = (n >= E) ? 1 : 0;
    int idd = n - s * E;
    int h = idd / HD, i = idd % HD;
    const float* W = (s ? Wk0 : Wq0) + (size_t)l * EE;
    for (int c = cg; c < E; c += 4) {
        const float* Wr = W + (size_t)c * E + h * HD;
        float acc = 0.f;
        if (mode == 0) {
            for (int d = 0; d < HD; ++d) acc += Wr[d] * fpS[d * HD + i];
        } else if (mode == 1) {
            for (int d = 0; d < HD; ++d) acc += Wr[d] * fpS[d * 64 + (i - i0)];
        } else {
            for (int d = 0; d < HD; ++d) acc += Wr[d] * fp[(size_t)d * HD + i];
        }
        Wt[(size_t)n * E + c] = bf16r(acc);
    }
}

// ---------------------------------------------------------------------------
// Batched bias fold
// ---------------------------------------------------------------------------
__global__ void biasfold_k(const float* __restrict__ bq0, const float* __restrict__ bk0,
                           const float* __restrict__ bv0, const float* __restrict__ fp0,
                           float* __restrict__ bqkv0, int E, int HD) {
    int l = blockIdx.z;
    const float* bq = bq0 + (size_t)l * E;
    const float* bk = bk0 + (size_t)l * E;
    const float* bv = bv0 + (size_t)l * E;
    const float* fp = fp0 + (size_t)l * HD * HD;
    float* bqkv = bqkv0 + (size_t)l * 3 * E;
    int c = blockIdx.x * 256 + threadIdx.x;
    if (c >= 3 * E) return;
    if (c < 2 * E) {
        int mat = c / E, cc = c % E, h = cc / HD, j = cc % HD;
        const float* bb = mat ? bk : bq;
        float s = 0.f;
        for (int d = 0; d < HD; ++d) s += bb[h * HD + d] * fp[(size_t)d * HD + j];
        bqkv[c] = s;
    } else {
        bqkv[c] = bv[c - 2 * E];
    }
}

// ---------------------------------------------------------------------------
// gemm2_k: 128x128x64 bf16 MFMA GEMM (proven). 1D grid, bijective XCD swizzle,
// n-fastest decomposition. op: 0 f32 store, 1 gelu->bf16, 2 f32 +=, 3 bf16.
// ---------------------------------------------------------------------------
__global__ __launch_bounds__(512) void gemm2_k(
        const unsigned short* __restrict__ A, int lda,
        const unsigned short* __restrict__ Bt, int ldbt,
        void* __restrict__ Cv, int ldc,
        const float* __restrict__ bias,
        int M, int Nn, int K, int op, int al, int nNt) {
    __shared__ unsigned short Ab[128 * 64];
    __shared__ unsigned short Bb[128 * 64];
    int t = threadIdx.x;
    int nwg = gridDim.x;
    int orig = blockIdx.x;
    int xcd = orig & 7, pos = orig >> 3;
    int q = nwg >> 3, r = nwg & 7;
    int wgid = (xcd < r ? xcd * (q + 1) : r * (q + 1) + (xcd - r) * q) + pos;
    int m0 = (wgid / nNt) * 128, n0 = (wgid % nNt) * 128;
    int w = t >> 6, lane = t & 63;
    int wm = w >> 2, wn = w & 3;
    int lrow = lane & 15, lk = lane >> 4;

    float4v acc[4][2];
#pragma unroll
    for (int fa = 0; fa < 4; ++fa)
#pragma unroll
        for (int fb = 0; fb < 2; ++fb) acc[fa][fb] = (float4v){0.f, 0.f, 0.f, 0.f};

    int srow8 = lane >> 3;
    int sch = lane & 7;
    bool fastA = al && (m0 + 128 <= M);
    bool fastB = al && (n0 + 128 <= Nn);

    for (int k0 = 0; k0 < K; k0 += 64) {
        bool fullK = (k0 + 64 <= K);
        __syncthreads();
#if USE_GLL
        if (fastA && fullK) {
#pragma unroll
            for (int it = 0; it < 2; ++it) {
                int rr = w * 16 + it * 8 + srow8;
                const unsigned short* g = A + (size_t)(m0 + rr) * lda + k0 + ((sch ^ (rr & 7)) << 3);
                __builtin_amdgcn_global_load_lds((const void*)g, (void*)&Ab[(w * 16 + it * 8) * 64], 16, 0, 0);
            }
        } else
#endif
        {
#pragma unroll
            for (int cc = 0; cc < 2; ++cc) {
                int c = t + cc * 512;
                int row = c >> 3, ch = c & 7;
                int gm = m0 + row, gk = k0 + ch * 8;
                short8v v = {0, 0, 0, 0, 0, 0, 0, 0};
                if (gm < M) {
                    if (al && gk + 8 <= K) {
                        v = *(const short8v*)(A + (size_t)gm * lda + gk);
                    } else {
                        const unsigned short* p = A + (size_t)gm * lda;
#pragma unroll
                        for (int j = 0; j < 8; ++j)
                            if (gk + j < K) v[j] = (short)p[gk + j];
                    }
                }
                *(short8v*)&Ab[row * 64 + ((ch ^ (row & 7)) << 3)] = v;
            }
        }
#if USE_GLL
        if (fastB && fullK) {
#pragma unroll
            for (int it = 0; it < 2; ++it) {
                int rr = w * 16 + it * 8 + srow8;
                const unsigned short* g = Bt + (size_t)(n0 + rr) * ldbt + k0 + ((sch ^ (rr & 7)) << 3);
                __builtin_amdgcn_global_load_lds((const void*)g, (void*)&Bb[(w * 16 + it * 8) * 64], 16, 0, 0);
            }
        } else
#endif
        {
#pragma unroll
            for (int cc = 0; cc < 2; ++cc) {
                int c = t + cc * 512;
                int row = c >> 3, ch = c & 7;
                int gn = n0 + row, gk = k0 + ch * 8;
                short8v v = {0, 0, 0, 0, 0, 0, 0, 0};
                if (gn < Nn) {
                    if (al && gk + 8 <= K) {
                        v = *(const short8v*)(Bt + (size_t)gn * ldbt + gk);
                    } else {
                        const unsigned short* p = Bt + (size_t)gn * ldbt;
#pragma unroll
                        for (int j = 0; j < 8; ++j)
                            if (gk + j < K) v[j] = (short)p[gk + j];
                    }
                }
                *(short8v*)&Bb[row * 64 + ((ch ^ (row & 7)) << 3)] = v;
            }
        }
        __syncthreads();
#pragma unroll
        for (int ks = 0; ks < 2; ++ks) {
            short8v af[4], bf[2];
#pragma unroll
            for (int fa = 0; fa < 4; ++fa) {
                int row = wm * 64 + fa * 16 + lrow;
                af[fa] = *(const short8v*)&Ab[row * 64 + (((ks * 4 + lk) ^ (row & 7)) << 3)];
            }
#pragma unroll
            for (int fb = 0; fb < 2; ++fb) {
                int row = wn * 32 + fb * 16 + lrow;
                bf[fb] = *(const short8v*)&Bb[row * 64 + (((ks * 4 + lk) ^ (row & 7)) << 3)];
            }
#pragma unroll
            for (int fa = 0; fa < 4; ++fa)
#pragma unroll
                for (int fb = 0; fb < 2; ++fb)
                    acc[fa][fb] = __builtin_amdgcn_mfma_f32_16x16x32_bf16(
                        af[fa], bf[fb], acc[fa][fb], 0, 0, 0);
        }
    }
    float* Cf = (float*)Cv;
    unsigned short* Cu = (unsigned short*)Cv;
#pragma unroll
    for (int fb = 0; fb < 2; ++fb) {
        int col = n0 + wn * 32 + fb * 16 + lrow;
        if (col >= Nn) continue;
        float bb = bias ? bias[col] : 0.f;
#pragma unroll
        for (int fa = 0; fa < 4; ++fa) {
#pragma unroll
            for (int q2 = 0; q2 < 4; ++q2) {
                int row = m0 + wm * 64 + fa * 16 + lk * 4 + q2;
                if (row >= M) continue;
                float v = acc[fa][fb][q2] + bb;
                size_t idx = (size_t)row * ldc + col;
                if (op == 0) Cf[idx] = v;
                else if (op == 1) Cu[idx] = bf16r(gelu_f(v));
                else if (op == 2) Cf[idx] += v;
                else Cu[idx] = bf16r(v);
            }
        }
    }
}

// ---------------------------------------------------------------------------
// Patch embed + cls + pos -> x f32. grid (N, B), block 256.
// ---------------------------------------------------------------------------
__global__ void embed_lds_k(const float* __restrict__ src, const float* __restrict__ cw,
                            const float* __restrict__ cb, const float* __restrict__ pos,
                            const float* __restrict__ cls, float* __restrict__ x,
                            int C, int IMG, int P, int m, int E, int N, int K) {
    extern __shared__ float patch[];
    int n = blockIdx.x, b = blockIdx.y, t = threadIdx.x;
    if (n == 0) {
        for (int e = t; e < E; e += 256)
            x[((size_t)b * N) * E + e] = cls[e] + pos[e];
        return;
    }
    int p = n - 1, ph = p / m, pw = p % m;
    int P2 = P * P;
    for (int mm = t; mm < K; mm += 256) {
        int c = mm / P2, rem = mm % P2, i = rem / P, j = rem % P;
        patch[mm] = src[(((size_t)b * C + c) * IMG + ph * P + i) * IMG + pw * P + j];
    }
    __syncthreads();
    for (int e = t; e < E; e += 256) {
        float acc = cb[e];
        const float* wr = cw + (size_t)e * K;
        for (int mm = 0; mm < K; ++mm) acc += patch[mm] * wr[mm];
        x[((size_t)b * N + n) * E + e] = acc + pos[(size_t)n * E + e];
    }
}

__global__ void embed_dir_k(const float* __restrict__ src, const float* __restrict__ cw,
                            const float* __restrict__ cb, const float* __restrict__ pos,
                            const float* __restrict__ cls, float* __restrict__ x,
                            int C, int IMG, int P, int m, int E, int N, int K) {
    int n = blockIdx.x, b = blockIdx.y, t = threadIdx.x;
    if (n == 0) {
        for (int e = t; e < E; e += 256)
            x[((size_t)b * N) * E + e] = cls[e] + pos[e];
        return;
    }
    int p = n - 1, ph = p / m, pw = p % m;
    int P2 = P * P;
    for (int e = t; e < E; e += 256) {
        float acc = cb[e];
        const float* wr = cw + (size_t)e * K;
        for (int mm = 0; mm < K; ++mm) {
            int c = mm / P2, rem = mm % P2, i = rem / P, j = rem % P;
            acc += src[(((size_t)b * C + c) * IMG + ph * P + i) * IMG + pw * P + j] * wr[mm];
        }
        x[((size_t)b * N + n) * E + e] = acc + pos[(size_t)n * E + e];
    }
}

// ---------------------------------------------------------------------------
// LayerNorm rows of x f32 -> xg bf16. grid ceil(TOK/4), block 256.
// float4-vectorized path when E%256==0 (G13), scalar fallback otherwise.
// ---------------------------------------------------------------------------
__global__ void ln_k(const float* __restrict__ x, const float* __restrict__ g,
                     const float* __restrict__ b, unsigned short* __restrict__ xg,
                     int TOK, int E, float invE) {
    int row = blockIdx.x * 4 + (threadIdx.x >> 6);
    int lane = threadIdx.x & 63;
    if (row >= TOK) return;
    const float* xr = x + (size_t)row * E;
    unsigned short* orow = xg + (size_t)row * E;
    if ((E & 255) == 0) {
        const float4v* xr4 = (const float4v*)xr;
        const float4v* g4p = (const float4v*)g;
        const float4v* b4p = (const float4v*)b;
        int n4 = E >> 2;
        float s = 0.f;
        for (int i = lane; i < n4; i += 64) {
            float4v v4 = xr4[i];
            s += (v4.x + v4.y) + (v4.z + v4.w);
        }
#pragma unroll
        for (int mm = 32; mm >= 1; mm >>= 1) s += __shfl_xor(s, mm, 64);
        float mean = s * invE;
        float vv = 0.f;
        for (int i = lane; i < n4; i += 64) {
            float4v v4 = xr4[i];
            float d0 = v4.x - mean, d1 = v4.y - mean, d2 = v4.z - mean, d3 = v4.w - mean;
            vv += (d0 * d0 + d1 * d1) + (d2 * d2 + d3 * d3);
        }
#pragma unroll
        for (int mm = 32; mm >= 1; mm >>= 1) vv += __shfl_xor(vv, mm, 64);
        float inv = rsqrtf(vv * invE + 1e-5f);
        for (int i = lane; i < n4; i += 64) {
            float4v v4 = xr4[i], g4 = g4p[i], b4 = b4p[i];
            short4v r;
            r[0] = (short)bf16r((v4.x - mean) * inv * g4.x + b4.x);
            r[1] = (short)bf16r((v4.y - mean) * inv * g4.y + b4.y);
            r[2] = (short)bf16r((v4.z - mean) * inv * g4.z + b4.z);
            r[3] = (short)bf16r((v4.w - mean) * inv * g4.w + b4.w);
            *(short4v*)&orow[i * 4] = r;
        }
    } else {
        float s = 0.f;
        for (int e = lane; e < E; e += 64) s += xr[e];
#pragma unroll
        for (int mm = 32; mm >= 1; mm >>= 1) s += __shfl_xor(s, mm, 64);
        float mean = s * invE;
        float v = 0.f;
        for (int e = lane; e < E; e += 64) { float d = xr[e] - mean; v += d * d; }
#pragma unroll
        for (int mm = 32; mm >= 1; mm >>= 1) v += __shfl_xor(v, mm, 64);
        float inv = rsqrtf(v * invE + 1e-5f);
        for (int e = lane; e < E; e += 64)
            orow[e] = bf16r((xr[e] - mean) * inv * g[e] + b[e]);
    }
}

// ---------------------------------------------------------------------------
// Attention core on bf16 qkv + fused LN2. grid (Gg, nimg), block 256.
// If stage=1, the 8 qkv rows are first staged into LDS (padded stride E3+8 to
// spread k-rows across banks), then scores/PV read LDS instead of re-reading
// L2 ~8x. LDS: H*64 floats (sc) + [stage? 8*(E3+8) shorts].
// ---------------------------------------------------------------------------
__global__ void attn_sm_k(const unsigned short* __restrict__ qkv, float* __restrict__ x,
                          unsigned short* __restrict__ xg,
                          const float* __restrict__ g2, const float* __restrict__ b2,
                          int img0, int N, int E, int H, int HD, float rscale,
                          float invE, int vec, int stage) {
    extern __shared__ float sc[];
    unsigned short* qs = (unsigned short*)(sc + H * 64);
    int g = blockIdx.x, im = blockIdx.y, t = threadIdx.x;
    int t0 = g * 8, nv = min(8, N - t0);
    int E3 = 3 * E;
    int lstr = E3 + 8;
    const unsigned short* qb = qkv + ((size_t)im * N + t0) * E3;
    size_t rowbase = ((size_t)(img0 + im)) * N + t0;
    float* xb = x + rowbase * E;

    if (stage) {
        for (int r = 0; r < nv; ++r) {
            const unsigned short* grow = qb + (size_t)r * E3;
            unsigned short* lrow = qs + r * lstr;
            for (int c = t * 8; c < E3; c += 2048)
                *(short8v*)&lrow[c] = *(const short8v*)&grow[c];
        }
        __syncthreads();
    }

    for (int idx = t; idx < H * 64; idx += 256) {
        int h = idx >> 6, qr = (idx >> 3) & 7, kr = idx & 7;
        float s = 0.f;
        if (qr < nv && kr < nv) {
            const unsigned short* qp;
            const unsigned short* kp;
            if (stage) {
                qp = qs + qr * lstr + h * HD;
                kp = qs + kr * lstr + E + h * HD;
            } else {
                qp = qb + (size_t)qr * E3 + h * HD;
                kp = qb + (size_t)kr * E3 + E + h * HD;
            }
            if (vec) {
                for (int d = 0; d < HD; d += 8) {
                    short8v qv = *(const short8v*)(qp + d);
                    short8v kv = *(const short8v*)(kp + d);
#pragma unroll
                    for (int j = 0; j < 8; ++j)
                        s += bf2f((unsigned short)qv[j]) * bf2f((unsigned short)kv[j]);
                }
            } else {
                for (int d = 0; d < HD; ++d)
                    s += bf2f(qp[d]) * bf2f(kp[d]);
            }
        }
        sc[idx] = s * rscale;
    }
    __syncthreads();
    for (int idx = t; idx < H * 8; idx += 256) {
        int h = idx >> 3, qr = idx & 7;
        if (qr < nv) {
            float* row = sc + h * 64 + qr * 8;
            float mx = -1e30f;
            for (int k = 0; k < nv; ++k) mx = fmaxf(mx, row[k]);
            float sum = 0.f;
            for (int k = 0; k < nv; ++k) { float e = expf(row[k] - mx); row[k] = e; sum += e; }
            float inv = 1.f / sum;
            for (int k = 0; k < nv; ++k) row[k] *= inv;
        }
    }
    __syncthreads();
    for (int c = t; c < E; c += 256) {
        int h = c / HD;
        const float* srow = sc + h * 64;
        float vcol[8];
#pragma unroll
        for (int k = 0; k < 8; ++k) {
            if (k < nv)
                vcol[k] = stage ? bf2f(qs[k * lstr + 2 * E + c])
                                : bf2f(qb[(size_t)k * E3 + 2 * E + c]);
            else vcol[k] = 0.f;
        }
        for (int r = 0; r < nv; ++r) {
            float o = 0.f;
#pragma unroll
            for (int k = 0; k < 8; ++k) o += srow[r * 8 + k] * vcol[k];
            xb[(size_t)r * E + c] += o;
        }
    }
    __syncthreads();
    int w = t >> 6, lane = t & 63;
#pragma unroll
    for (int rr = 0; rr < 2; ++rr) {
        int r = w + rr * 4;
        if (r >= nv) continue;
        const float* xr = xb + (size_t)r * E;
        float s = 0.f;
        for (int e = lane; e < E; e += 64) s += xr[e];
#pragma unroll
        for (int mm = 32; mm >= 1; mm >>= 1) s += __shfl_xor(s, mm, 64);
        float mean = s * invE;
        float v = 0.f;
        for (int e = lane; e < E; e += 64) { float d = xr[e] - mean; v += d * d; }
#pragma unroll
        for (int mm = 32; mm >= 1; mm >>= 1) v += __shfl_xor(v, mm, 64);
        float inv = rsqrtf(v * invE + 1e-5f);
        unsigned short* orow = xg + (rowbase + r) * E;
        for (int e = lane; e < E; e += 64)
            orow[e] = bf16r((xr[e] - mean) * inv * g2[e] + b2[e]);
    }
}

// ---------------------------------------------------------------------------
__global__ void head_k(const float* __restrict__ fw, const float* __restrict__ fb,
                       const float* __restrict__ x, float* __restrict__ out,
                       int Bc, int N, int E, int NC) {
    int idx = blockIdx.x * 256 + threadIdx.x;
    if (idx < Bc * NC) {
        int b = idx / NC, nc = idx % NC;
        float acc = fb[nc];
        const float* xr = x + (size_t)b * N * E;
        for (int e = 0; e < E; ++e) acc += xr[e] * fw[(size_t)e * NC + nc];
        out[idx] = acc;
    }
}

// ---------------------------------------------------------------------------
static int isqrt_i(long long v) {
    if (v < 0) return -1;
    long long r = (long long)(sqrt((double)v) + 0.5);
    while (r * r > v) --r;
    while ((r + 1) * (r + 1) <= v) ++r;
    return (int)r;
}

extern "C" void kernel_launch(void* const* d_in, const int* in_sizes, int n_in,
                              void* d_out, int out_size, void* d_ws, size_t ws_size,
                              hipStream_t stream) {
    float* out = (float*)d_out;
    int nblk_out = (out_size + 255) / 256;
#define DUMP(code, val) do { \
        dump_k<<<nblk_out, 256, 0, stream>>>(out, out_size, (float)((code) * 1000000.0 + (double)(val))); \
        return; } while (0)

    if (n_in != 22) DUMP(1, n_in < 999999 ? n_in : 999999);
    const int* S = in_sizes;

    int E = S[2];
    if (E <= 0 || S[4] != E) DUMP(2, 4);
    if (S[6] % E) DUMP(2, 6);
    int L = S[6] / E;
    if (L <= 0) DUMP(2, 6);
    long long EE = (long long)E * E;
    if (S[5] != L * EE || S[7] != L * EE || S[9] != L * EE) DUMP(2, 5);
    if (S[8] != L * E || S[10] != L * E) DUMP(2, 8);
    if (S[12] != L * E || S[13] != L * E || S[14] != L * E || S[15] != L * E) DUMP(2, 12);
    if (S[19] != L * E) DUMP(2, 19);
    if (S[11] % L) DUMP(2, 11);
    int HD = isqrt_i(S[11] / L);
    if ((long long)HD * HD * L != S[11] || HD <= 0 || E % HD) DUMP(3, HD > 0 ? HD : 0);
    int H = E / HD;
    if (S[17] % L) DUMP(2, 17);
    int FF = S[17] / L;
    if (S[16] != (long long)L * E * FF) DUMP(2, 16);
    if (S[18] != (long long)L * FF * E) DUMP(2, 18);
    if (S[3] % E) DUMP(2, 3);
    int N = S[3] / E;
    int m = isqrt_i(N - 1);
    if (m <= 0 || m * m != N - 1) DUMP(4, N < 999999 ? N : 999999);
    int NC = S[21];
    if (NC <= 0 || S[20] != (long long)E * NC) DUMP(2, 20);
    if (out_size % NC) DUMP(8, out_size < 999999 ? out_size : 999999);
    int Bc = out_size / NC;
    if (S[1] % E) DUMP(2, 1);
    int K = S[1] / E;
    static const int corder[12] = {3, 4, 1, 2, 8, 16, 6, 12, 32, 64, 24, 48};
    int C = -1, P = -1;
    for (int ci = 0; ci < 12; ++ci) {
        int c = corder[ci];
        if (K % c) continue;
        int p = isqrt_i(K / c);
        if (p > 0 && p * p * c == K) {
            long long img = (long long)p * m;
            if ((long long)Bc * c * img * img == S[0]) { C = c; P = p; break; }
        }
    }
    if (C < 0) DUMP(5, K < 999999 ? K : 999999);
    int IMG = P * m;
    int TOK = Bc * N;
    int Gg = (N + 7) / 8;
    int E3 = 3 * E;
    int al = ((E % 8) == 0 && (FF % 8) == 0) ? 1 : 0;
    int vecA = (al && (HD % 8) == 0) ? 1 : 0;

    int fmode;
    if (HD <= 64) fmode = 0;
    else if ((E % 64) == 0 && HD <= 256) fmode = 1;
    else fmode = 2;
    size_t fold_sh = (fmode == 0) ? (size_t)HD * HD * 4
                   : (fmode == 1) ? (size_t)HD * 64 * 4 : 16;

    size_t b_x  = ((size_t)TOK * E * 4 + 255) & ~(size_t)255;
    size_t b_xg = ((size_t)TOK * E * 2 + 255) & ~(size_t)255;
    size_t s_wt  = ((size_t)E3 * E * 2 + 255) & ~(size_t)255;
    size_t s_wff = ((size_t)E * FF * 2 + 255) & ~(size_t)255;
    size_t s_bq  = ((size_t)E3 * 4 + 255) & ~(size_t)255;
    size_t perL = s_wt + 2 * s_wff + s_bq;
    size_t minbuf = (size_t)N * E3 * 2;
    size_t fb2 = (size_t)128 * FF * 2;
    if (fb2 > minbuf) minbuf = fb2;

    int LW;
    if (b_x + b_xg + perL * L + minbuf <= ws_size) LW = L;
    else if (b_x + b_xg + perL + minbuf <= ws_size) LW = 1;
    else { DUMP(6, (double)(ws_size >> 20)); }

    char* wsb = (char*)d_ws;
    size_t off = 0;
    float* x = (float*)(wsb + off); off += b_x;
    unsigned short* xg = (unsigned short*)(wsb + off); off += b_xg;
    unsigned short* Wt_base = (unsigned short*)(wsb + off); off += s_wt * LW;
    unsigned short* w1t_base = (unsigned short*)(wsb + off); off += s_wff * LW;
    unsigned short* w2t_base = (unsigned short*)(wsb + off); off += s_wff * LW;
    float* bq_base = (float*)(wsb + off); off += s_bq * LW;
    size_t buf_bytes = ws_size - off;
    unsigned short* bufu = (unsigned short*)(wsb + off);

    int CHI = (int)(buf_bytes / ((size_t)N * E3 * 2));
    if (CHI > Bc) CHI = Bc;
    long long chf_l = (long long)(buf_bytes / ((size_t)FF * 2));
    chf_l = (chf_l / 128) * 128;
    int CHF = chf_l > TOK ? TOK : (int)chf_l;
    if (CHI < 1 || CHF < 128) DUMP(6, (double)(ws_size >> 20));

    const float* src = (const float*)d_in[0];
    const float* cw  = (const float*)d_in[1];
    const float* cb  = (const float*)d_in[2];
    const float* pos = (const float*)d_in[3];
    const float* cls = (const float*)d_in[4];
    const float* Wq  = (const float*)d_in[5];
    const float* bq  = (const float*)d_in[6];
    const float* Wk  = (const float*)d_in[7];
    const float* bk  = (const float*)d_in[8];
    const float* Wv  = (const float*)d_in[9];
    const float* bv  = (const float*)d_in[10];
    const float* fp  = (const float*)d_in[11];
    const float* g1  = (const float*)d_in[12];
    const float* b1  = (const float*)d_in[13];
    const float* g2  = (const float*)d_in[14];
    const float* b2  = (const float*)d_in[15];
    const float* w1  = (const float*)d_in[16];
    const float* bb1 = (const float*)d_in[17];
    const float* w2  = (const float*)d_in[18];
    const float* bb2 = (const float*)d_in[19];
    const float* fcw = (const float*)d_in[20];
    const float* fcb = (const float*)d_in[21];

    float invE = 1.f / (float)E;
    float rscale = 1.f / sqrtf((float)HD);
    size_t wtL = (size_t)E3 * E;
    size_t wffL = (size_t)E * FF;

    size_t patch_sh = (size_t)K * sizeof(float);
    if (patch_sh <= 48000)
        embed_lds_k<<<dim3(N, Bc), 256, patch_sh, stream>>>(src, cw, cb, pos, cls, x,
                                                            C, IMG, P, m, E, N, K);
    else
        embed_dir_k<<<dim3(N, Bc), 256, 0, stream>>>(src, cw, cb, pos, cls, x,
                                                     C, IMG, P, m, E, N, K);

    int gx_fold = (2 * E + 63) / 64;
    if (LW == L) {
        fold_k<<<dim3(gx_fold, 1, L), 256, fold_sh, stream>>>(Wq, Wk, fp, Wt_base, E, HD, fmode);
        tc_k<<<dim3((E + 31) / 32, (E + 31) / 32, L), 256, 0, stream>>>(
            Wv, Wt_base + (size_t)2 * E * E, E, E, EE, wtL);
        tc_k<<<dim3((E + 31) / 32, (FF + 31) / 32, L), 256, 0, stream>>>(
            w1, w1t_base, E, FF, (long long)E * FF, wffL);
        tc_k<<<dim3((FF + 31) / 32, (E + 31) / 32, L), 256, 0, stream>>>(
            w2, w2t_base, FF, E, (long long)E * FF, wffL);
        biasfold_k<<<dim3((E3 + 255) / 256, 1, L), 256, 0, stream>>>(
            bq, bk, bv, fp, bq_base, E, HD);
    }

    int ln_grid = (TOK + 3) / 4;
    // attention LDS: stage qkv rows when it fits (+bank-spread padding)
    int stageA = (al && ((size_t)H * 64 * 4 + (size_t)8 * (E3 + 8) * 2 <= 60000)) ? 1 : 0;
    size_t attn_sh = (size_t)H * 64 * 4 + (stageA ? (size_t)8 * (E3 + 8) * 2 : 0);

    for (int l = 0; l < L; ++l) {
        int lw = (LW == L) ? l : 0;
        unsigned short* Wt_l  = Wt_base + (size_t)lw * (s_wt / 2);
        unsigned short* w1t_l = w1t_base + (size_t)lw * (s_wff / 2);
        unsigned short* w2t_l = w2t_base + (size_t)lw * (s_wff / 2);
        float* bq_l = (float*)((char*)bq_base + (size_t)lw * s_bq);

        if (LW != L) {
            fold_k<<<dim3(gx_fold, 1, 1), 256, fold_sh, stream>>>(
                Wq + (size_t)l * EE, Wk + (size_t)l * EE, fp + (size_t)l * HD * HD,
                Wt_l, E, HD, fmode);
            tc_k<<<dim3((E + 31) / 32, (E + 31) / 32, 1), 256, 0, stream>>>(
                Wv + (size_t)l * EE, Wt_l + (size_t)2 * E * E, E, E, 0, 0);
            tc_k<<<dim3((E + 31) / 32, (FF + 31) / 32, 1), 256, 0, stream>>>(
                w1 + (size_t)l * E * FF, w1t_l, E, FF, 0, 0);
            tc_k<<<dim3((FF + 31) / 32, (E + 31) / 32, 1), 256, 0, stream>>>(
                w2 + (size_t)l * FF * E, w2t_l, FF, E, 0, 0);
            biasfold_k<<<dim3((E3 + 255) / 256, 1, 1), 256, 0, stream>>>(
                bq + (size_t)l * E, bk + (size_t)l * E, bv + (size_t)l * E,
                fp + (size_t)l * HD * HD, bq_l, E, HD);
        }

        // ---- LN1 -> xg bf16
        ln_k<<<ln_grid, 256, 0, stream>>>(x, g1 + (size_t)l * E, b1 + (size_t)l * E,
                                          xg, TOK, E, invE);
        // ---- QKV GEMM (bf16 out) + attention (+ fused LN2 -> xg)
        for (int img0 = 0; img0 < Bc; img0 += CHI) {
            int nimg = Bc - img0 < CHI ? Bc - img0 : CHI;
            int ntok = nimg * N;
            int nMt = (ntok + 127) / 128, nNt = (E3 + 127) / 128;
            gemm2_k<<<nMt * nNt, 512, 0, stream>>>(
                xg + (size_t)img0 * N * E, E, Wt_l, E, bufu, E3, bq_l,
                ntok, E3, E, 3, al, nNt);
            attn_sm_k<<<dim3(Gg, nimg), 256, attn_sh, stream>>>(
                bufu, x, xg, g2 + (size_t)l * E, b2 + (size_t)l * E,
                img0, N, E, H, HD, rscale, invE, vecA, stageA);
        }
        // ---- FFN (xg already = LN2(x))
        for (int tok0 = 0; tok0 < TOK; tok0 += CHF) {
            int ntok = TOK - tok0 < CHF ? TOK - tok0 : CHF;
            int nMt = (ntok + 127) / 128;
            int nNt1 = (FF + 127) / 128, nNt2 = (E + 127) / 128;
            gemm2_k<<<nMt * nNt1, 512, 0, stream>>>(
                xg + (size_t)tok0 * E, E, w1t_l, E, bufu, FF,
                bb1 + (size_t)l * FF, ntok, FF, E, 1, al, nNt1);
            gemm2_k<<<nMt * nNt2, 512, 0, stream>>>(
                bufu, FF, w2t_l, FF, x + (size_t)tok0 * E, E,
                bb2 + (size_t)l * E, ntok, E, FF, 2, al, nNt2);
        }
    }
    head_k<<<nblk_out, 256, 0, stream>>>(fcw, fcb, x, out, Bc, N, E, NC);
#undef DUMP
}